// Round 5
// baseline (607.658 us; speedup 1.0000x reference)
//
#include <hip/hip_runtime.h>
#include <hip/hip_bf16.h>

#define N_NODES 100000
#define N_EDGES 1600000

#define NBKT 782                 // ceil(N_NODES / 128)
#define BKT_CHUNK 13334          // ceil(N_EDGES / 120)
#define SCAT_BLOCKS 120

#define AGG_NODES 32             // nodes per aggG block (100000 = 3125 * 32 exactly)
#define AGG_CHUNKS 3125
#define COL_CAP 1536             // LDS-cached col window (fallback to global past this)
#define LP 72                    // padded LDS row length in shorts (64 + 8)

typedef __attribute__((ext_vector_type(8))) short short8v;
typedef __attribute__((ext_vector_type(4))) float float4v;

__device__ __forceinline__ unsigned short f2bf(float f) {
    unsigned int u = __float_as_uint(f);
    u = (u + 0x7FFFu + ((u >> 16) & 1u)) >> 16;   // RTNE
    return (unsigned short)u;
}
__device__ __forceinline__ float bf2f(unsigned short b) {
    return __uint_as_float((unsigned int)b << 16);
}

// ---------------- CSR build via 2-level bucket counting sort ----------------

__global__ __launch_bounds__(256) void bkt_count_kernel(const int* __restrict__ ei, int* __restrict__ bucket_cnt) {
    __shared__ int h[NBKT];
    int tid = threadIdx.x;
    for (int i = tid; i < NBKT; i += 256) h[i] = 0;
    __syncthreads();
    int start = blockIdx.x * BKT_CHUNK;
    int end = start + BKT_CHUNK; if (end > N_EDGES) end = N_EDGES;
    for (int i = start + tid; i < end; i += 256) {
        int d = ei[N_EDGES + i];
        atomicAdd(&h[d >> 7], 1);
    }
    __syncthreads();
    for (int i = tid; i < NBKT; i += 256) {
        int c = h[i];
        if (c) atomicAdd(&bucket_cnt[i], c);
    }
}

__global__ __launch_bounds__(256) void bkt_scan_kernel(const int* __restrict__ bucket_cnt,
                                                       int* __restrict__ bucket_off, int* __restrict__ cursor) {
    __shared__ int ps[256];
    int tid = threadIdx.x;
    int base = tid * 4;
    int v[4];
    int s = 0;
    #pragma unroll
    for (int i = 0; i < 4; i++) {
        v[i] = (base + i < NBKT) ? bucket_cnt[base + i] : 0;
        s += v[i];
    }
    ps[tid] = s;
    __syncthreads();
    for (int off = 1; off < 256; off <<= 1) {
        int y = 0;
        if (tid >= off) y = ps[tid - off];
        __syncthreads();
        if (tid >= off) ps[tid] += y;
        __syncthreads();
    }
    int run = ps[tid] - s;   // exclusive
    #pragma unroll
    for (int i = 0; i < 4; i++) {
        if (base + i < NBKT) { bucket_off[base + i] = run; cursor[base + i] = run; }
        run += v[i];
    }
    if (tid == 0) bucket_off[NBKT] = N_EDGES;
}

__global__ __launch_bounds__(256) void bkt_scatter_kernel(const int* __restrict__ ei, int* __restrict__ cursor,
                                                          int2* __restrict__ pairs) {
    __shared__ int h[NBKT];
    __shared__ int basearr[NBKT];
    int tid = threadIdx.x;
    for (int i = tid; i < NBKT; i += 256) h[i] = 0;
    __syncthreads();
    int start = blockIdx.x * BKT_CHUNK;
    int end = start + BKT_CHUNK; if (end > N_EDGES) end = N_EDGES;
    for (int i = start + tid; i < end; i += 256) {
        int d = ei[N_EDGES + i];
        atomicAdd(&h[d >> 7], 1);
    }
    __syncthreads();
    for (int b = tid; b < NBKT; b += 256) {
        int c = h[b];
        basearr[b] = c ? atomicAdd(&cursor[b], c) : 0;
        h[b] = 0;
    }
    __syncthreads();
    for (int i = start + tid; i < end; i += 256) {
        int s = ei[i];
        int d = ei[N_EDGES + i];
        int bkt = d >> 7;
        int pos = basearr[bkt] + atomicAdd(&h[bkt], 1);
        pairs[pos] = make_int2(s, d);
    }
}

__global__ __launch_bounds__(256) void bkt_deg_kernel(const int2* __restrict__ pairs, const int* __restrict__ bucket_off,
                                                      int* __restrict__ deg) {
    __shared__ int c[128];
    int tid = threadIdx.x;
    if (tid < 128) c[tid] = 0;
    __syncthreads();
    int s0 = bucket_off[blockIdx.x], s1 = bucket_off[blockIdx.x + 1];
    for (int i = s0 + tid; i < s1; i += 256) {
        int d = pairs[i].y;
        atomicAdd(&c[d & 127], 1);
    }
    __syncthreads();
    int node = blockIdx.x * 128 + tid;
    if (tid < 128 && node < N_NODES) deg[node] = c[tid];
}

__global__ __launch_bounds__(256) void bkt_fill_kernel(const int2* __restrict__ pairs, const int* __restrict__ bucket_off,
                                                       const int* __restrict__ row_ptr, int* __restrict__ col) {
    __shared__ int rp[128];
    __shared__ int c[128];
    int tid = threadIdx.x;
    int node = blockIdx.x * 128 + tid;
    if (tid < 128) {
        rp[tid] = (node < N_NODES) ? row_ptr[node] : 0;
        c[tid] = 0;
    }
    __syncthreads();
    int s0 = bucket_off[blockIdx.x], s1 = bucket_off[blockIdx.x + 1];
    for (int i = s0 + tid; i < s1; i += 256) {
        int2 e = pairs[i];
        int dl = e.y & 127;
        int pos = rp[dl] + atomicAdd(&c[dl], 1);
        col[pos] = e.x;
    }
}

// ---------------- scan of deg -> row_ptr ----------------
#define SCAN_ELEMS 1024
__global__ __launch_bounds__(256) void scan_a_kernel(const int* __restrict__ deg, int* __restrict__ bsum) {
    __shared__ int lds[256];
    int tid = threadIdx.x;
    int base = blockIdx.x * SCAN_ELEMS + tid * 4;
    int s = 0;
    #pragma unroll
    for (int i = 0; i < 4; i++) {
        int idx = base + i;
        s += (idx < N_NODES) ? deg[idx] : 0;
    }
    lds[tid] = s;
    __syncthreads();
    for (int off = 128; off; off >>= 1) {
        if (tid < off) lds[tid] += lds[tid + off];
        __syncthreads();
    }
    if (tid == 0) bsum[blockIdx.x] = lds[0];
}

__global__ void scan_b_kernel(int* __restrict__ bsum, int nb) {
    if (threadIdx.x == 0 && blockIdx.x == 0) {
        int acc = 0;
        for (int i = 0; i < nb; i++) { int v = bsum[i]; bsum[i] = acc; acc += v; }
    }
}

__global__ __launch_bounds__(256) void scan_c_kernel(const int* __restrict__ deg, const int* __restrict__ bsum,
                                                     int* __restrict__ row_ptr) {
    __shared__ int lds[256];
    int tid = threadIdx.x;
    int base = blockIdx.x * SCAN_ELEMS + tid * 4;
    int v[4];
    int s = 0;
    #pragma unroll
    for (int i = 0; i < 4; i++) {
        int idx = base + i;
        v[i] = (idx < N_NODES) ? deg[idx] : 0;
        s += v[i];
    }
    lds[tid] = s;
    __syncthreads();
    for (int off = 1; off < 256; off <<= 1) {
        int y = 0;
        if (tid >= off) y = lds[tid - off];
        __syncthreads();
        if (tid >= off) lds[tid] += y;
        __syncthreads();
    }
    int run = bsum[blockIdx.x] + lds[tid] - s;
    #pragma unroll
    for (int i = 0; i < 4; i++) {
        int idx = base + i;
        if (idx < N_NODES) row_ptr[idx] = run;
        run += v[i];
    }
    if (blockIdx.x == 0 && tid == 0) row_ptr[N_NODES] = N_EDGES;
}

__global__ __launch_bounds__(256) void deginv_kernel(const int* __restrict__ deg, float* __restrict__ deg_inv) {
    int i = blockIdx.x * 256 + threadIdx.x;
    if (i < N_NODES) deg_inv[i] = 1.0f / fmaxf((float)deg[i], 1.0f);
}

// ---------------- x (fp32 Nx64) -> grouped bf16 slabs xg[g][node][16], g=0..3 ----------------
__global__ __launch_bounds__(256) void xbf_kernel(const float* __restrict__ x, unsigned short* __restrict__ xg) {
    int idx = blockIdx.x * 256 + threadIdx.x;   // one float4 per thread
    if (idx < N_NODES * 16) {
        int node = idx >> 4;
        int f0 = (idx & 15) * 4;
        float4 v = *(const float4*)(x + (size_t)idx * 4);
        ushort4 o;
        o.x = f2bf(v.x); o.y = f2bf(v.y); o.z = f2bf(v.z); o.w = f2bf(v.w);
        *(ushort4*)(xg + (size_t)(f0 >> 4) * (N_NODES * 16) + (size_t)node * 16 + (f0 & 15)) = o;
    }
}

// ---------------- grouped mean-aggregation ----------------
// block = (chunk, g): g = blockIdx.x & ((1<<gshift)-1), chunk = blockIdx.x >> gshift.
// Gathers 16-feature slab g of src (32 B/row) for AGG_NODES dst nodes; 8 lanes/node,
// 2 feats/lane. col window LDS-cached. With blockIdx%8 round-robin over XCDs, each
// XCD's L2 holds one 3.2 MB slab.
__global__ __launch_bounds__(256) void aggG_kernel(const unsigned short* __restrict__ src,
                                                   unsigned short* __restrict__ dst,
                                                   const int* __restrict__ row_ptr, const int* __restrict__ col,
                                                   const float* __restrict__ deg_inv, int gshift) {
    __shared__ int cols[COL_CAP];
    int tid = threadIdx.x;
    int g = blockIdx.x & ((1 << gshift) - 1);
    int chunk = blockIdx.x >> gshift;
    int n0 = chunk * AGG_NODES;
    int n1 = n0 + AGG_NODES; if (n1 > N_NODES) n1 = N_NODES;
    const unsigned short* sg = src + (size_t)g * (N_NODES * 16);
    unsigned short* dg = dst + (size_t)g * (N_NODES * 16);
    int s0 = row_ptr[n0];
    int cnt = row_ptr[n1] - s0;
    int ccap = cnt < COL_CAP ? cnt : COL_CAP;
    for (int idx = tid; idx < ccap; idx += 256) cols[idx] = col[s0 + idx];
    __syncthreads();

    int nloc = tid >> 3;       // 0..31
    int ld = tid & 7;          // feats [ld*2, ld*2+2)
    int i = n0 + nloc;
    if (i >= N_NODES) return;
    int s = row_ptr[i], e = row_ptr[i + 1];
    float a0 = 0.f, a1 = 0.f;
    int t = s;
    for (; t + 1 < e; t += 2) {
        int li0 = t - s0, li1 = t + 1 - s0;
        int j0 = (li0 < ccap) ? cols[li0] : col[t];
        int j1 = (li1 < ccap) ? cols[li1] : col[t + 1];
        ushort2 u0 = *(const ushort2*)(sg + (size_t)j0 * 16 + ld * 2);
        ushort2 u1 = *(const ushort2*)(sg + (size_t)j1 * 16 + ld * 2);
        a0 += bf2f(u0.x) + bf2f(u1.x);
        a1 += bf2f(u0.y) + bf2f(u1.y);
    }
    if (t < e) {
        int li = t - s0;
        int j = (li < ccap) ? cols[li] : col[t];
        ushort2 u = *(const ushort2*)(sg + (size_t)j * 16 + ld * 2);
        a0 += bf2f(u.x);
        a1 += bf2f(u.y);
    }
    float di = deg_inv[i];
    ushort2 o;
    o.x = f2bf(a0 * di);
    o.y = f2bf(a1 * di);
    *(ushort2*)(dg + (size_t)i * 16 + ld * 2) = o;
}

// ---------------- weight prep (transposed bf16) ----------------
// layer1: A = [x(k<64) | aggx(k>=64)], Bt1[n][k], n in [0,256), k in [0,128):
//   n<128:  k<64 -> Wr1[k][n];      k>=64 -> Wl1[k-64][n]
//   n>=128: k<64 -> Wres[k][n-128]; k>=64 -> 0
__global__ __launch_bounds__(256) void wprep1_kernel(const float* __restrict__ Wr1, const float* __restrict__ Wl1,
                                                     const float* __restrict__ Wres, unsigned short* __restrict__ Bt) {
    int idx = blockIdx.x * 256 + threadIdx.x;   // n*128 + k
    if (idx >= 256 * 128) return;
    int n = idx >> 7;
    int k = idx & 127;
    float v;
    if (n < 128) v = (k < 64) ? Wr1[k * 128 + n] : Wl1[(k - 64) * 128 + n];
    else         v = (k < 64) ? Wres[k * 128 + (n - 128)] : 0.f;
    Bt[idx] = f2bf(v);
}

// layers 2/3: A = [h(k<128) | aggh(k>=128)], Bt[n][k] = k<128 ? Wr[k][n] : Wl[k-128][n]
__global__ __launch_bounds__(256) void wprep23_kernel(const float* __restrict__ Wl, const float* __restrict__ Wr,
                                                      unsigned short* __restrict__ Bt) {
    int idx = blockIdx.x * 256 + threadIdx.x;   // n*256 + k
    if (idx >= 128 * 256) return;
    int n = idx >> 8;
    int k = idx & 255;
    float v = (k < 128) ? Wr[k * 128 + n] : Wl[(k - 128) * 128 + n];
    Bt[idx] = f2bf(v);
}

// ---------------- MFMA bf16 GEMM over grouped-slab A ----------------
// A grouped: element (m, kk) at A[(kk>>4)*(N*16) + m*16 + (kk&15)]. Bt row-major [Nout][Kt].
// If Cbf != null (layers 2/3): out 128 cols, fused +bias, relu, grouped bf16 store
// (in-place over A slabs 0..7 is safe: each block reads only its own rows before writing).
// Else (layer 1): fp32 store to Cf, ldc 256, col offset n0.
__global__ __launch_bounds__(256) void mgemm_kernel(const unsigned short* __restrict__ A,
                                                    const unsigned short* __restrict__ Bt, int M, int Kt,
                                                    float* __restrict__ Cf, const float* __restrict__ bias,
                                                    unsigned short* __restrict__ Cbf) {
    __shared__ unsigned short As[128 * LP];
    __shared__ unsigned short Bs[128 * LP];
    int tid = threadIdx.x;
    int m0 = blockIdx.x * 128;
    int n0 = blockIdx.y * 128;

    int lane = tid & 63;
    int wave = tid >> 6;
    int wm = (wave & 1) * 64;
    int wn = (wave >> 1) * 64;
    int lm = lane & 15;
    int lk = (lane >> 4) * 8;

    float4v acc[4][4];
    #pragma unroll
    for (int i = 0; i < 4; i++)
        #pragma unroll
        for (int j = 0; j < 4; j++) acc[i][j] = (float4v)0.f;

    int sr = tid >> 3;          // staging row 0..31
    int sc = (tid & 7) * 8;     // staging col (shorts)

    for (int ks = 0; ks < Kt; ks += 64) {
        if (ks) __syncthreads();
        int kk = ks + sc;
        const unsigned short* Ab = A + (size_t)(kk >> 4) * (N_NODES * 16) + (kk & 15);
        #pragma unroll
        for (int rr = 0; rr < 128; rr += 32) {
            int r = sr + rr;
            int gm = m0 + r; if (gm > M - 1) gm = M - 1;
            ulonglong2 va = *(const ulonglong2*)(Ab + (size_t)gm * 16);
            *(ulonglong2*)&As[r * LP + sc] = va;
            ulonglong2 vb = *(const ulonglong2*)(Bt + (size_t)(n0 + r) * Kt + kk);
            *(ulonglong2*)&Bs[r * LP + sc] = vb;
        }
        __syncthreads();

        #pragma unroll
        for (int k0 = 0; k0 < 64; k0 += 32) {
            short8v af[4], bf[4];
            #pragma unroll
            for (int i = 0; i < 4; i++)
                af[i] = *(const short8v*)&As[(wm + i * 16 + lm) * LP + k0 + lk];
            #pragma unroll
            for (int j = 0; j < 4; j++)
                bf[j] = *(const short8v*)&Bs[(wn + j * 16 + lm) * LP + k0 + lk];
            #pragma unroll
            for (int i = 0; i < 4; i++)
                #pragma unroll
                for (int j = 0; j < 4; j++)
                    acc[i][j] = __builtin_amdgcn_mfma_f32_16x16x32_bf16(af[i], bf[j], acc[i][j], 0, 0, 0);
        }
    }

    int r0b = (lane >> 4) * 4;
    #pragma unroll
    for (int i = 0; i < 4; i++) {
        #pragma unroll
        for (int j = 0; j < 4; j++) {
            int cc = wn + j * 16 + (lane & 15);
            #pragma unroll
            for (int r = 0; r < 4; r++) {
                int m = m0 + wm + i * 16 + r0b + r;
                if (m < M) {
                    if (Cbf != nullptr) {
                        float v = fmaxf(acc[i][j][r] + bias[cc], 0.f);
                        Cbf[(size_t)(cc >> 4) * (N_NODES * 16) + (size_t)m * 16 + (cc & 15)] = f2bf(v);
                    } else {
                        Cf[(size_t)m * 256 + n0 + cc] = acc[i][j][r];
                    }
                }
            }
        }
    }
}

// ---------------- layer1 epilogue: t=U[:,0:128]+b1 -> LN -> relu -> + U[:,128:256]+bres -> grouped bf16 ----------------
__global__ __launch_bounds__(256) void ln_kernel(const float* __restrict__ U, const float* __restrict__ b1,
                                                 const float* __restrict__ ln_g, const float* __restrict__ ln_b,
                                                 const float* __restrict__ bres, unsigned short* __restrict__ act) {
    int tid = threadIdx.x;
    int grp = tid >> 7;
    int f = tid & 127;
    int i = blockIdx.x * 2 + grp;
    bool valid = i < N_NODES;
    float t = 0.f;
    if (valid) t = U[(size_t)i * 256 + f] + b1[f];
    float s = t, s2 = t * t;
    #pragma unroll
    for (int off = 32; off; off >>= 1) {
        s += __shfl_down(s, off);
        s2 += __shfl_down(s2, off);
    }
    __shared__ float rs[4], rs2[4];
    int wave = tid >> 6;
    if ((tid & 63) == 0) { rs[wave] = s; rs2[wave] = s2; }
    __syncthreads();
    float sum = rs[grp * 2] + rs[grp * 2 + 1];
    float sumsq = rs2[grp * 2] + rs2[grp * 2 + 1];
    float mu = sum * (1.f / 128.f);
    float var = sumsq * (1.f / 128.f) - mu * mu;
    float r = rsqrtf(var + 1e-5f);
    if (valid) {
        float y = (t - mu) * r * ln_g[f] + ln_b[f];
        y = fmaxf(y, 0.f);
        y += U[(size_t)i * 256 + 128 + f] + bres[f];
        act[(size_t)(f >> 4) * (N_NODES * 16) + (size_t)i * 16 + (f & 15)] = f2bf(y);
    }
}

// ---------------- layer4 ----------------
__global__ __launch_bounds__(256) void pq_kernel(const unsigned short* __restrict__ act, const float* __restrict__ Wl4,
                                                 const float* __restrict__ Wr4, const float* __restrict__ b4,
                                                 float* __restrict__ p, float* __restrict__ q) {
    int tid = threadIdx.x;
    int lane = tid & 63;
    int w = tid >> 6;
    int i = blockIdx.x * 4 + w;
    if (i >= N_NODES) return;
    int g0 = lane >> 4, o0 = lane & 15;
    float a = bf2f(act[(size_t)g0 * (N_NODES * 16) + (size_t)i * 16 + o0]);
    float b = bf2f(act[(size_t)(g0 + 4) * (N_NODES * 16) + (size_t)i * 16 + o0]);
    float pp = a * Wl4[lane] + b * Wl4[64 + lane];
    float qq = a * Wr4[lane] + b * Wr4[64 + lane];
    #pragma unroll
    for (int off = 32; off; off >>= 1) {
        pp += __shfl_down(pp, off);
        qq += __shfl_down(qq, off);
    }
    if (lane == 0) { p[i] = pp; q[i] = qq + b4[0]; }
}

__global__ __launch_bounds__(256) void final_kernel(const float* __restrict__ p, const float* __restrict__ q,
                                                    const int* __restrict__ row_ptr, const int* __restrict__ col,
                                                    const float* __restrict__ deg_inv, float* __restrict__ out) {
    int i = blockIdx.x * 256 + threadIdx.x;
    if (i >= N_NODES) return;
    int s = row_ptr[i], e = row_ptr[i + 1];
    float acc = 0.f;
    for (int t = s; t < e; t++) acc += p[col[t]];
    out[i] = acc * deg_inv[i] + q[i];
}

// ---------------- launch ----------------

extern "C" void kernel_launch(void* const* d_in, const int* in_sizes, int n_in,
                              void* d_out, int out_size, void* d_ws, size_t ws_size,
                              hipStream_t stream) {
    const float* x    = (const float*)d_in[0];
    const int*   ei   = (const int*)d_in[1];
    const float* Wl1  = (const float*)d_in[2];
    const float* Wr1  = (const float*)d_in[3];
    const float* b1   = (const float*)d_in[4];
    const float* ln_g = (const float*)d_in[5];
    const float* ln_b = (const float*)d_in[6];
    const float* Wres = (const float*)d_in[7];
    const float* bres = (const float*)d_in[8];
    const float* Wl2  = (const float*)d_in[9];
    const float* Wr2  = (const float*)d_in[10];
    const float* b2   = (const float*)d_in[11];
    const float* Wl3  = (const float*)d_in[12];
    const float* Wr3  = (const float*)d_in[13];
    const float* b3   = (const float*)d_in[14];
    const float* Wl4  = (const float*)d_in[15];
    const float* Wr4  = (const float*)d_in[16];
    const float* b4   = (const float*)d_in[17];
    float* out = (float*)d_out;

    char* w = (char*)d_ws;
    size_t off = 0;
    auto alloc = [&](size_t bytes) -> void* {
        off = (off + 255) & ~(size_t)255;
        void* pp = w + off;
        off += bytes;
        return pp;
    };

    int*   deg        = (int*)alloc(N_NODES * 4);
    int*   row_ptr    = (int*)alloc((N_NODES + 1) * 4);
    int*   bsum       = (int*)alloc(512);
    int*   col        = (int*)alloc(N_EDGES * 4);
    float* deg_inv    = (float*)alloc(N_NODES * 4);
    int*   bucket_cnt = (int*)alloc(NBKT * 4);
    int*   bucket_off = (int*)alloc((NBKT + 1) * 4);
    int*   cursor     = (int*)alloc(NBKT * 4);
    unsigned short* Btw  = (unsigned short*)alloc(128 * 256 * 2);
    unsigned short* xg   = (unsigned short*)alloc((size_t)8 * N_NODES * 16 * 2);   // [x g0-3 | aggx g4-7]
    unsigned short* act  = (unsigned short*)alloc((size_t)16 * N_NODES * 16 * 2);  // [h g0-7 | aggh g8-15]
    float* U       = (float*)alloc((size_t)N_NODES * 256 * 4);
    float* p       = (float*)alloc(N_NODES * 4);
    float* q       = (float*)alloc(N_NODES * 4);
    // pairs aliases U: CSR build completes before U is first written (layer-1 GEMM)
    int2* pairs = (int2*)U;
    (void)ws_size; (void)n_in; (void)in_sizes; (void)out_size;

    const int NB = (N_NODES + 255) / 256;
    const int SCB = (N_NODES + SCAN_ELEMS - 1) / SCAN_ELEMS;
    const int MB = (N_NODES + 127) / 128;   // 782
    unsigned short* aggh = act + (size_t)8 * N_NODES * 16;

    // --- CSR build (bucket counting sort) ---
    hipMemsetAsync(bucket_cnt, 0, NBKT * 4, stream);
    bkt_count_kernel<<<SCAT_BLOCKS, 256, 0, stream>>>(ei, bucket_cnt);
    bkt_scan_kernel<<<1, 256, 0, stream>>>(bucket_cnt, bucket_off, cursor);
    bkt_scatter_kernel<<<SCAT_BLOCKS, 256, 0, stream>>>(ei, cursor, pairs);
    bkt_deg_kernel<<<NBKT, 256, 0, stream>>>(pairs, bucket_off, deg);
    scan_a_kernel<<<SCB, 256, 0, stream>>>(deg, bsum);
    scan_b_kernel<<<1, 64, 0, stream>>>(bsum, SCB);
    scan_c_kernel<<<SCB, 256, 0, stream>>>(deg, bsum, row_ptr);
    bkt_fill_kernel<<<NBKT, 256, 0, stream>>>(pairs, bucket_off, row_ptr, col);
    deginv_kernel<<<NB, 256, 0, stream>>>(deg, deg_inv);

    // --- layer 1: xg = [x | mean-agg(x)] grouped bf16; GEMM -> U fp32; LN -> act ---
    xbf_kernel<<<(N_NODES * 16 + 255) / 256, 256, 0, stream>>>(x, xg);
    aggG_kernel<<<AGG_CHUNKS * 4, 256, 0, stream>>>(xg, xg + (size_t)4 * N_NODES * 16,
                                                    row_ptr, col, deg_inv, 2);
    wprep1_kernel<<<128, 256, 0, stream>>>(Wr1, Wl1, Wres, Btw);
    mgemm_kernel<<<dim3(MB, 2), 256, 0, stream>>>(xg, Btw, N_NODES, 128, U, nullptr, nullptr);
    ln_kernel<<<(N_NODES + 1) / 2, 256, 0, stream>>>(U, b1, ln_g, ln_b, bres, act);

    // --- layer 2: agg(h) -> aggh; GEMM [h|aggh] -> h (in-place, fused bias+relu) ---
    aggG_kernel<<<AGG_CHUNKS * 8, 256, 0, stream>>>(act, aggh, row_ptr, col, deg_inv, 3);
    wprep23_kernel<<<128, 256, 0, stream>>>(Wl2, Wr2, Btw);
    mgemm_kernel<<<dim3(MB, 1), 256, 0, stream>>>(act, Btw, N_NODES, 256, nullptr, b2, act);

    // --- layer 3 ---
    aggG_kernel<<<AGG_CHUNKS * 8, 256, 0, stream>>>(act, aggh, row_ptr, col, deg_inv, 3);
    wprep23_kernel<<<128, 256, 0, stream>>>(Wl3, Wr3, Btw);
    mgemm_kernel<<<dim3(MB, 1), 256, 0, stream>>>(act, Btw, N_NODES, 256, nullptr, b3, act);

    // --- layer 4 ---
    pq_kernel<<<(N_NODES + 3) / 4, 256, 0, stream>>>(act, Wl4, Wr4, b4, p, q);
    final_kernel<<<NB, 256, 0, stream>>>(p, q, row_ptr, col, deg_inv, out);
}